// Round 10
// baseline (3131.188 us; speedup 1.0000x reference)
//
#include <hip/hip_runtime.h>
#include <hip/hip_fp16.h>
#include <math.h>

#define N_NODES 50000
#define E_EDGES 800000
#define E_TOT   850000   // E + N self loops
#define HC 128
#define NHEAD 4
#define LIN 256
#define OUTC 10
#define NG 64
#define NEG_SLOPE 0.2f

// (dst, src-tile)-sorted CSR (R16). R21: persistent co-resident aggr with
// soft barriers (R6-proven) + WRITE-TIME ownership stash (replaces R19/R20's
// shfl-prefix-search, which produced absmax 4.3 — logic unverifiable).
// Stash: per wave, 64-entry (sv, w4[4], k) buffer filled segment-by-segment,
// flushed through the V_old-shape 8-deep gather.
#define NT 5
#define TILE_N 10000
#define NSEG (N_NODES * NT)     // 250000 (dst,tile) cells
#define SCAN_BLOCKS 245         // 245 * 1024 cells >= NSEG
#define NBLK 1024               // 4 blocks/CU x 256 CU, co-resident
#define NWAVE (NBLK * 4)
#define NPW 13                  // consecutive nodes per wave: 4096*13 >= 50000

__device__ __forceinline__ float lrelu(float v) { return v > 0.f ? v : NEG_SLOPE * v; }
__device__ __forceinline__ int iclamp(int v, int lo, int hi) {
  return v < lo ? lo : (v > hi ? hi : v);
}

typedef _Float16 half8v __attribute__((ext_vector_type(8)));
typedef float    float4v __attribute__((ext_vector_type(4)));

// ---------------------------------------------------------------------------
// MFMA GEMM + attention logits (R18 A-staged version, -25us proven).
// ---------------------------------------------------------------------------
__global__ __launch_bounds__(256) void k_gemm_mfma(
    const float* __restrict__ x, const float* __restrict__ W,
    const float* __restrict__ a_s, const float* __restrict__ a_d,
    __half* __restrict__ h, float* __restrict__ asrc, float* __restrict__ adst) {
  __shared__ _Float16 Wt[128 * 136];       // W^T fp16, padded row stride 136
  __shared__ _Float16 xt[64 * 136];        // x-tile fp16 (later reused as hst)
  __shared__ float aS[HC], aD[HC];
  _Float16 (*hst)[16][136] = (_Float16 (*)[16][136])xt;  // epilogue alias
  int tid = threadIdx.x;
  if (tid < HC) { aS[tid] = a_s[tid]; aD[tid] = a_d[tid]; }
  for (int i = 0; i < 64; i++) {
    int idx = tid + i * 256;               // 16384 elements
    int k = idx >> 7, n = idx & 127;
    Wt[n * 136 + k] = (_Float16)W[idx];
  }
  {
    int rowbase0 = blockIdx.x * 64;
#pragma unroll
    for (int i = 0; i < 8; i++) {
      int idx = tid + i * 256;             // f4 index 0..2047
      int row = idx >> 5, c4 = idx & 31;
      int grow = rowbase0 + row;
      if (grow > N_NODES - 1) grow = N_NODES - 1;  // clamp; stores guarded
      float4 f4 = ((const float4*)x)[(size_t)grow * 32 + c4];
      _Float16* p = &xt[row * 136 + c4 * 4];
      p[0] = (_Float16)f4.x; p[1] = (_Float16)f4.y;
      p[2] = (_Float16)f4.z; p[3] = (_Float16)f4.w;
    }
  }
  __syncthreads();

  int wv = tid >> 6, lane = tid & 63;
  int quad = lane >> 4, low = lane & 15;
  int rowbase = blockIdx.x * 64 + wv * 16;

  float4v acc[8];
#pragma unroll
  for (int t = 0; t < 8; t++) acc[t] = (float4v){0.f, 0.f, 0.f, 0.f};

#pragma unroll
  for (int k4 = 0; k4 < 4; k4++) {
    int kb = k4 * 32 + quad * 8;
    half8v af = *(const half8v*)&xt[(wv * 16 + low) * 136 + kb];
    half8v bf[8];
#pragma unroll
    for (int t = 0; t < 8; t++)
      bf[t] = *(const half8v*)&Wt[(t * 16 + low) * 136 + kb];
#pragma unroll
    for (int t = 0; t < 8; t++)
      acc[t] = __builtin_amdgcn_mfma_f32_16x16x32_f16(af, bf[t], acc[t], 0, 0, 0);
  }
  __syncthreads();   // all xt reads done before reuse as hst

#pragma unroll
  for (int t = 0; t < 8; t++)
#pragma unroll
    for (int r = 0; r < 4; r++)
      hst[wv][quad * 4 + r][t * 16 + low] = (_Float16)acc[t][r];
  __syncthreads();

  {
    int r = lane >> 2, part = lane & 3;
    int grow = rowbase + r;
    if (grow < N_NODES) {
      const float4* src = (const float4*)&hst[wv][r][part * 32];
      float4* dst = (float4*)(h + (size_t)grow * HC + part * 32);
#pragma unroll
      for (int i = 0; i < 4; i++) dst[i] = src[i];
    }
  }
  {
    int grow = rowbase + low;
    float ss = 0.f, dd = 0.f;
#pragma unroll
    for (int i = 0; i < 32; i++) {
      float hv = (float)hst[wv][low][quad * 32 + i];
      ss += hv * aS[quad * 32 + i];
      dd += hv * aD[quad * 32 + i];
    }
    if (grow < N_NODES) {
      asrc[grow * NHEAD + quad] = ss;
      adst[grow * NHEAD + quad] = dd;
    }
  }
}

// ---------------------------------------------------------------------------
// CSR build, counting-sorted by (dst, src_tile). Hierarchical scan (R16).
// ---------------------------------------------------------------------------
__global__ __launch_bounds__(256) void k_hist(
    const int* __restrict__ dst, const int* __restrict__ src,
    int* __restrict__ degT) {
  int e = blockIdx.x * 256 + threadIdx.x;
  if (e >= E_TOT) return;
  int d, s;
  if (e < E_EDGES) { d = dst[e]; s = src[e]; } else { d = s = e - E_EDGES; }
  int t = s / TILE_N;
  atomicAdd(&degT[d * NT + t], 1);
}

__global__ __launch_bounds__(256) void k_scanA(
    const int* __restrict__ degT, int* __restrict__ bsum) {
  __shared__ int ps[256];
  int tid = threadIdx.x, b = blockIdx.x;
  int base = b * 1024 + tid * 4;
  int s = 0;
#pragma unroll
  for (int i = 0; i < 4; i++) {
    int idx = base + i;
    if (idx < NSEG) s += degT[idx];
  }
  ps[tid] = s;
  __syncthreads();
  for (int off = 128; off > 0; off >>= 1) {
    if (tid < off) ps[tid] += ps[tid + off];
    __syncthreads();
  }
  if (tid == 0) bsum[b] = ps[0];
}

// scanB: exclusive scan of block sums (+ pooled zero + barrier counters zero)
__global__ __launch_bounds__(256) void k_scanB(
    const int* __restrict__ bsum, int* __restrict__ boff,
    unsigned* __restrict__ pooled, int* __restrict__ pc) {
  __shared__ int ps[256];
  int tid = threadIdx.x;
  {
    uint4* p4 = (uint4*)pooled;
#pragma unroll
    for (int i = 0; i < 8; i++) p4[tid * 8 + i] = make_uint4(0u, 0u, 0u, 0u);
  }
  if (tid < 24) pc[tid] = 0;   // 3 layers x 8 soft-barrier counters
  int s = (tid < SCAN_BLOCKS) ? bsum[tid] : 0;
  ps[tid] = s;
  __syncthreads();
  for (int off = 1; off < 256; off <<= 1) {
    int v = (tid >= off) ? ps[tid - off] : 0;
    __syncthreads();
    ps[tid] += v;
    __syncthreads();
  }
  if (tid < SCAN_BLOCKS) boff[tid] = ps[tid] - s;  // exclusive
}

__global__ __launch_bounds__(256) void k_scanC(
    const int* __restrict__ degT, const int* __restrict__ boff,
    int* __restrict__ offT) {
  __shared__ int ps[256];
  int tid = threadIdx.x, b = blockIdx.x;
  int base = b * 1024 + tid * 4;
  int d[4];
  int s = 0;
#pragma unroll
  for (int i = 0; i < 4; i++) {
    int idx = base + i;
    d[i] = (idx < NSEG) ? degT[idx] : 0;
    s += d[i];
  }
  ps[tid] = s;
  __syncthreads();
  for (int off = 1; off < 256; off <<= 1) {
    int v = (tid >= off) ? ps[tid - off] : 0;
    __syncthreads();
    ps[tid] += v;
    __syncthreads();
  }
  int run = boff[b] + ps[tid] - s;
#pragma unroll
  for (int i = 0; i < 4; i++) {
    int idx = base + i;
    if (idx < NSEG) {
      offT[idx] = run;
      run += d[i];
      if (idx == NSEG - 1) offT[NSEG] = run;
    }
  }
}

__global__ __launch_bounds__(256) void k_scatter(
    const int* __restrict__ src, const int* __restrict__ dst,
    const int* __restrict__ offT, int* __restrict__ cntT,
    int* __restrict__ csr_src) {
  int e = blockIdx.x * 256 + threadIdx.x;
  if (e >= E_TOT) return;
  int s, d;
  if (e < E_EDGES) { s = src[e]; d = dst[e]; } else { s = d = e - E_EDGES; }
  int t = s / TILE_N;
  int pos = offT[d * NT + t] + atomicAdd(&cntT[d * NT + t], 1);
  csr_src[pos] = s;
}

#define BFLY_MAX4(m0, m1, m2, m3)                         \
  _Pragma("unroll") for (int off = 1; off < 64; off <<= 1) { \
    m0 = fmaxf(m0, __shfl_xor(m0, off));                  \
    m1 = fmaxf(m1, __shfl_xor(m1, off));                  \
    m2 = fmaxf(m2, __shfl_xor(m2, off));                  \
    m3 = fmaxf(m3, __shfl_xor(m3, off));                  \
  }
#define BFLY_SUM4(s0, s1, s2, s3)                         \
  _Pragma("unroll") for (int off = 1; off < 64; off <<= 1) { \
    s0 += __shfl_xor(s0, off);                            \
    s1 += __shfl_xor(s1, off);                            \
    s2 += __shfl_xor(s2, off);                            \
    s3 += __shfl_xor(s3, off);                            \
  }

// ---------------------------------------------------------------------------
// R21: persistent co-resident aggr, time-aligned tiles, write-time stash.
// Tile phase t: sweep the wave's 13 (node,tile) segments in order. For each
// <=64-edge chunk: lanes 0..n-1 compute (sv, w4) from L2-resident asrc and
// stash at [pos+lane] with ownership k recorded AT WRITE TIME (no prefix
// search -- R19/R20's unverifiable piece removed). Flush via the V_old-shape
// 8-deep gather (LAW: one 256B h-row span per instruction) whenever the
// 64-entry buffer would overflow, and at tile end. pos/n/L/k all wave-
// uniform -> no divergent control. Accumulate into axy[k][lane] LDS.
// ---------------------------------------------------------------------------
__global__ __launch_bounds__(256, 4) void k_aggr(
    const int* __restrict__ offT, const int* __restrict__ csr_src,
    const float* __restrict__ asrc, const float* __restrict__ adst,
    const __half* __restrict__ h, const float* __restrict__ bias,
    const int* __restrict__ batch, float* __restrict__ out_h,
    unsigned* __restrict__ pooled, int* __restrict__ pc, int do_pool) {
  __shared__ float2 axy[4][NPW][64];        // 26.6 KB accumulators
  __shared__ float mst[4][NPW][NHEAD][3];   // m, adh, 1/S
  __shared__ float w4e[4][64][4];
  __shared__ int   sve[4][64];
  __shared__ int   nke[4][64];
  __shared__ int   ok_s;
  int tid = threadIdx.x, wl = tid >> 6, lane = tid & 63;
  int wid = blockIdx.x * 4 + wl;
  int nodebase = wid * NPW;
  int head = lane >> 4;

  // ---- phase 0: softmax stats (no h traffic) — R6-proven ----
  for (int k = 0; k < NPW; k++) {
    int node = nodebase + k;
    if (node >= N_NODES) break;
    axy[wl][k][lane] = make_float2(0.f, 0.f);
    int lo = offT[node * NT], hi = offT[node * NT + NT];
    int deg = hi - lo;
    float4 ad4 = ((const float4*)adst)[node];
    float m0, m1, m2, m3, s0, s1, s2, s3;
    if (deg <= 64) {
      int j = lo + lane;
      bool valid = j < hi;
      int sv = valid ? csr_src[j] : 0;
      float4 a4 = ((const float4*)asrc)[sv];
      float e0 = valid ? lrelu(a4.x + ad4.x) : -1e30f;
      float e1 = valid ? lrelu(a4.y + ad4.y) : -1e30f;
      float e2 = valid ? lrelu(a4.z + ad4.z) : -1e30f;
      float e3 = valid ? lrelu(a4.w + ad4.w) : -1e30f;
      m0 = e0; m1 = e1; m2 = e2; m3 = e3;
      BFLY_MAX4(m0, m1, m2, m3)
      float w0 = expf(e0 - m0), w1 = expf(e1 - m1);
      float w2 = expf(e2 - m2), w3 = expf(e3 - m3);
      s0 = w0; s1 = w1; s2 = w2; s3 = w3;
      BFLY_SUM4(s0, s1, s2, s3)
    } else {
      float M0 = -1e30f, M1 = -1e30f, M2 = -1e30f, M3 = -1e30f;
      for (int c = lo; c < hi; c += 64) {
        int j = c + lane;
        bool valid = j < hi;
        int sv = valid ? csr_src[j] : 0;
        float4 a4 = ((const float4*)asrc)[sv];
        float e0 = valid ? lrelu(a4.x + ad4.x) : -1e30f;
        float e1 = valid ? lrelu(a4.y + ad4.y) : -1e30f;
        float e2 = valid ? lrelu(a4.z + ad4.z) : -1e30f;
        float e3 = valid ? lrelu(a4.w + ad4.w) : -1e30f;
        BFLY_MAX4(e0, e1, e2, e3)
        M0 = fmaxf(M0, e0); M1 = fmaxf(M1, e1);
        M2 = fmaxf(M2, e2); M3 = fmaxf(M3, e3);
      }
      float S0 = 0.f, S1 = 0.f, S2 = 0.f, S3 = 0.f;
      for (int c = lo; c < hi; c += 64) {
        int j = c + lane;
        bool valid = j < hi;
        int sv = valid ? csr_src[j] : 0;
        float4 a4 = ((const float4*)asrc)[sv];
        float e0 = valid ? lrelu(a4.x + ad4.x) : -1e30f;
        float e1 = valid ? lrelu(a4.y + ad4.y) : -1e30f;
        float e2 = valid ? lrelu(a4.z + ad4.z) : -1e30f;
        float e3 = valid ? lrelu(a4.w + ad4.w) : -1e30f;
        float w0 = expf(e0 - M0), w1 = expf(e1 - M1);
        float w2 = expf(e2 - M2), w3 = expf(e3 - M3);
        float t0 = w0, t1 = w1, t2 = w2, t3 = w3;
        BFLY_SUM4(t0, t1, t2, t3)
        S0 += t0; S1 += t1; S2 += t2; S3 += t3;
      }
      m0 = M0; m1 = M1; m2 = M2; m3 = M3;
      s0 = S0; s1 = S1; s2 = S2; s3 = S3;
    }
    if (lane < 4) {
      float mm = lane == 0 ? m0 : lane == 1 ? m1 : lane == 2 ? m2 : m3;
      float ss = lane == 0 ? s0 : lane == 1 ? s1 : lane == 2 ? s2 : s3;
      float ad = lane == 0 ? ad4.x : lane == 1 ? ad4.y : lane == 2 ? ad4.z : ad4.w;
      mst[wl][k][lane][0] = mm;
      mst[wl][k][lane][1] = ad;
      mst[wl][k][lane][2] = 1.f / ss;
    }
  }
  __syncthreads();   // publish mst/axy; align waves within block

  bool coh = true;
  int expect = gridDim.x;
#define SOFT_BAR(idx)                                                        \
  {                                                                          \
    __syncthreads();                                                         \
    if (tid == 0) {                                                          \
      __hip_atomic_fetch_add(&pc[idx], 1, __ATOMIC_ACQ_REL,                  \
                             __HIP_MEMORY_SCOPE_AGENT);                      \
      int ok = 1;                                                            \
      if (coh) {                                                             \
        int it = 0;                                                          \
        while (__hip_atomic_load(&pc[idx], __ATOMIC_ACQUIRE,                 \
                                 __HIP_MEMORY_SCOPE_AGENT) < expect) {       \
          if (++it > 1000) { ok = 0; break; }                                \
          __builtin_amdgcn_s_sleep(2);                                       \
        }                                                                    \
      } else ok = 0;                                                         \
      ok_s = ok;                                                             \
    }                                                                        \
    __syncthreads();                                                         \
    coh = coh && (ok_s != 0);                                                \
  }

  SOFT_BAR(0)

#define CONSUME(P)                                                           \
  {                                                                          \
    int jj = 0;                                                              \
    for (; jj + 8 <= (P); jj += 8) {                                         \
      float2 hv[8]; float wv[8]; int nv[8];                                  \
      _Pragma("unroll")                                                      \
      for (int u = 0; u < 8; u++) {                                          \
        int iu = sve[wl][jj + u];                                            \
        wv[u] = w4e[wl][jj + u][head];                                       \
        nv[u] = nke[wl][jj + u];                                             \
        hv[u] = __half22float2(*(const __half2*)(h + (size_t)iu * HC + lane * 2)); \
      }                                                                      \
      _Pragma("unroll")                                                      \
      for (int u = 0; u < 8; u++) {                                          \
        float2 a = axy[wl][nv[u]][lane];                                     \
        a.x += wv[u] * hv[u].x;                                              \
        a.y += wv[u] * hv[u].y;                                              \
        axy[wl][nv[u]][lane] = a;                                            \
      }                                                                      \
    }                                                                        \
    for (; jj < (P); jj++) {                                                 \
      int iu = sve[wl][jj];                                                  \
      float wu = w4e[wl][jj][head];                                          \
      int nu = nke[wl][jj];                                                  \
      float2 hu = __half22float2(*(const __half2*)(h + (size_t)iu * HC + lane * 2)); \
      float2 a = axy[wl][nu][lane];                                          \
      a.x += wu * hu.x;                                                      \
      a.y += wu * hu.y;                                                      \
      axy[wl][nu][lane] = a;                                                 \
    }                                                                        \
  }

  // ---- tile phases: write-time-ownership stash + 8-deep consume ----
  for (int t = 0; t < NT; t++) {
    int pos = 0;
    for (int k = 0; k < NPW; k++) {
      int node = nodebase + k;
      if (node >= N_NODES) break;
      int s0 = offT[node * NT + t];
      int L  = offT[node * NT + t + 1] - s0;
      for (int c = 0; c < L; c += 64) {
        int n = (L - c < 64) ? (L - c) : 64;
        if (pos + n > 64) { CONSUME(pos); pos = 0; }
        if (lane < n) {
          int sv = csr_src[s0 + c + lane];
          sv = iclamp(sv, 0, N_NODES - 1);   // safety clamp (cheap)
          float4 a4 = ((const float4*)asrc)[sv];
          float w0 = expf(lrelu(a4.x + mst[wl][k][0][1]) - mst[wl][k][0][0]);
          float w1 = expf(lrelu(a4.y + mst[wl][k][1][1]) - mst[wl][k][1][0]);
          float w2 = expf(lrelu(a4.z + mst[wl][k][2][1]) - mst[wl][k][2][0]);
          float w3 = expf(lrelu(a4.w + mst[wl][k][3][1]) - mst[wl][k][3][0]);
          sve[wl][pos + lane] = sv;
          nke[wl][pos + lane] = k;
          *(float4*)&w4e[wl][pos + lane][0] = make_float4(w0, w1, w2, w3);
        }
        pos += n;
      }
    }
    CONSUME(pos);
    if (t < NT - 1) SOFT_BAR(1 + t)
  }
#undef CONSUME
#undef SOFT_BAR

  // ---- epilogue: normalize, bias, relu, store (+pool) — R6-proven ----
  float2 b = *(const float2*)(bias + lane * 2);
  for (int k = 0; k < NPW; k++) {
    int node = nodebase + k;
    if (node >= N_NODES) break;
    float rd = mst[wl][k][head][2];
    float vx = fmaxf(axy[wl][k][lane].x * rd + b.x, 0.f);
    float vy = fmaxf(axy[wl][k][lane].y * rd + b.y, 0.f);
    *(float2*)(out_h + (size_t)node * HC + lane * 2) = make_float2(vx, vy);
    if (do_pool) {
      int g = batch[node];
      unsigned* pp = pooled + g * HC + lane * 2;
      // post-relu values >= 0: bit compare == float compare; init 0 matches
      // the reference's where(isfinite, pooled, 0) empty-graph guard.
      atomicMax(pp + 0, __float_as_uint(vx));
      atomicMax(pp + 1, __float_as_uint(vy));
    }
  }
}

// final head: out[g] = (pooled[g] @ Wlin + blin) @ Wout + bout ; 1 block/graph
__global__ __launch_bounds__(256) void k_mlp(
    const float* __restrict__ pooled, const float* __restrict__ Wlin,
    const float* __restrict__ blin, const float* __restrict__ Wout,
    const float* __restrict__ bout, float* __restrict__ out) {
  __shared__ float p[HC];
  __shared__ float z[LIN];
  int g = blockIdx.x, tid = threadIdx.x;
  if (tid < HC) p[tid] = pooled[g * HC + tid];
  __syncthreads();
  float zv = blin[tid];
  for (int k = 0; k < HC; k++) zv += p[k] * Wlin[k * LIN + tid];
  z[tid] = zv;
  __syncthreads();
  if (tid < OUTC) {
    float o = bout[tid];
    for (int k = 0; k < LIN; k++) o += z[k] * Wout[k * OUTC + tid];
    out[g * OUTC + tid] = o;
  }
}

extern "C" void kernel_launch(void* const* d_in, const int* in_sizes, int n_in,
                              void* d_out, int out_size, void* d_ws, size_t ws_size,
                              hipStream_t stream) {
  const float* x     = (const float*)d_in[0];
  const int*   ei    = (const int*)d_in[1];
  const int*   batch = (const int*)d_in[2];
  const float* Wl[3] = {(const float*)d_in[3], (const float*)d_in[7], (const float*)d_in[11]};
  const float* As[3] = {(const float*)d_in[4], (const float*)d_in[8], (const float*)d_in[12]};
  const float* Ad[3] = {(const float*)d_in[5], (const float*)d_in[9], (const float*)d_in[13]};
  const float* Bi[3] = {(const float*)d_in[6], (const float*)d_in[10], (const float*)d_in[14]};
  const float* Wlin  = (const float*)d_in[15];
  const float* blin  = (const float*)d_in[16];
  const float* Wout  = (const float*)d_in[17];
  const float* bout  = (const float*)d_in[18];
  float* out = (float*)d_out;

  // workspace layout (float offsets)
  float* ws = (float*)d_ws;
  __half*   h       = (__half*)ws;                 // N*128 halves (3.2M fl)
  float*    nodeB   = ws + 3200000;                // N*128 fp32   (6.4M fl)
  float*    asrc    = ws + 9600000;                // N*4
  float*    adst    = ws + 9800000;                // N*4
  int*      degT    = (int*)(ws + 10000000);       // 250k (adjacent to cntT)
  int*      cntT    = (int*)(ws + 10250000);       // 250k
  int*      offT    = (int*)(ws + 10500000);       // 250001
  int*      csr_src = (int*)(ws + 10750004);       // E_TOT (+pad)
  unsigned* pooled  = (unsigned*)(ws + 11600008);  // 64*128
  int*      bsum    = (int*)(ws + 11608200);       // 245
  int*      boff    = (int*)(ws + 11608456);       // 245
  int*      pc      = (int*)(ws + 11608704);       // 24 barrier counters

  const int* srcp = ei;
  const int* dstp = ei + E_EDGES;

  hipMemsetAsync(degT, 0, 2 * NSEG * sizeof(int), stream);  // degT + cntT

  // (dst, src_tile)-sorted CSR — built once, reused by all 3 layers
  k_hist<<<(E_TOT + 255) / 256, 256, 0, stream>>>(dstp, srcp, degT);
  k_scanA<<<SCAN_BLOCKS, 256, 0, stream>>>(degT, bsum);
  k_scanB<<<1, 256, 0, stream>>>(bsum, boff, pooled, pc);
  k_scanC<<<SCAN_BLOCKS, 256, 0, stream>>>(degT, boff, offT);
  k_scatter<<<(E_TOT + 255) / 256, 256, 0, stream>>>(srcp, dstp, offT, cntT, csr_src);

  const float* lin_in = x;
  for (int L = 0; L < 3; L++) {
    k_gemm_mfma<<<(N_NODES + 63) / 64, 256, 0, stream>>>(
        lin_in, Wl[L], As[L], Ad[L], h, asrc, adst);
    k_aggr<<<NBLK, 256, 0, stream>>>(
        offT, csr_src, asrc, adst, h, Bi[L], batch,
        nodeB, pooled, pc + L * 8, (L == 2) ? 1 : 0);
    lin_in = nodeB;
  }
  k_mlp<<<NG, 256, 0, stream>>>((const float*)pooled, Wlin, blin, Wout, bout, out);
}

// Round 11
// 2790.278 us; speedup vs baseline: 1.1222x; 1.1222x over previous
//
#include <hip/hip_runtime.h>
#include <hip/hip_fp16.h>
#include <math.h>

#define N_NODES 50000
#define E_EDGES 800000
#define E_TOT   850000   // E + N self loops
#define HC 128
#define NHEAD 4
#define LIN 256
#define OUTC 10
#define NG 64
#define NEG_SLOPE 0.2f

// (dst, src-tile)-sorted CSR (R16). R22 = R21 compute VERBATIM (passed,
// FETCH 53GB) + HIERARCHICAL soft barrier. R21's flat barrier = 1024-way
// single-line contention (~150us/barrier x 6 = the 930us stall, VALUBusy 7%).
// New: 8 group counters (64B-separated, blockIdx&7 ~ XCD-local), leader ->
// top counter (8-way), last leader sets 8 go-flags; spin on group-local flag.
#define NT 5
#define TILE_N 10000
#define NSEG (N_NODES * NT)     // 250000 (dst,tile) cells
#define SCAN_BLOCKS 245         // 245 * 1024 cells >= NSEG
#define NBLK 1024               // 4 blocks/CU x 256 CU, co-resident
#define NPW 13                  // consecutive nodes per wave: 4096*13 >= 50000
#define BAR_STRIDE 256          // ints per barrier phase (8 cnt + 8 flag + top)
#define PC_PER_LAYER (NT * BAR_STRIDE)   // 5 phases x 256 = 1280 ints

__device__ __forceinline__ float lrelu(float v) { return v > 0.f ? v : NEG_SLOPE * v; }
__device__ __forceinline__ int iclamp(int v, int lo, int hi) {
  return v < lo ? lo : (v > hi ? hi : v);
}

typedef _Float16 half8v __attribute__((ext_vector_type(8)));
typedef float    float4v __attribute__((ext_vector_type(4)));

// ---------------------------------------------------------------------------
// MFMA GEMM + attention logits (R18 A-staged version, -25us proven).
// ---------------------------------------------------------------------------
__global__ __launch_bounds__(256) void k_gemm_mfma(
    const float* __restrict__ x, const float* __restrict__ W,
    const float* __restrict__ a_s, const float* __restrict__ a_d,
    __half* __restrict__ h, float* __restrict__ asrc, float* __restrict__ adst) {
  __shared__ _Float16 Wt[128 * 136];       // W^T fp16, padded row stride 136
  __shared__ _Float16 xt[64 * 136];        // x-tile fp16 (later reused as hst)
  __shared__ float aS[HC], aD[HC];
  _Float16 (*hst)[16][136] = (_Float16 (*)[16][136])xt;  // epilogue alias
  int tid = threadIdx.x;
  if (tid < HC) { aS[tid] = a_s[tid]; aD[tid] = a_d[tid]; }
  for (int i = 0; i < 64; i++) {
    int idx = tid + i * 256;               // 16384 elements
    int k = idx >> 7, n = idx & 127;
    Wt[n * 136 + k] = (_Float16)W[idx];
  }
  {
    int rowbase0 = blockIdx.x * 64;
#pragma unroll
    for (int i = 0; i < 8; i++) {
      int idx = tid + i * 256;             // f4 index 0..2047
      int row = idx >> 5, c4 = idx & 31;
      int grow = rowbase0 + row;
      if (grow > N_NODES - 1) grow = N_NODES - 1;  // clamp; stores guarded
      float4 f4 = ((const float4*)x)[(size_t)grow * 32 + c4];
      _Float16* p = &xt[row * 136 + c4 * 4];
      p[0] = (_Float16)f4.x; p[1] = (_Float16)f4.y;
      p[2] = (_Float16)f4.z; p[3] = (_Float16)f4.w;
    }
  }
  __syncthreads();

  int wv = tid >> 6, lane = tid & 63;
  int quad = lane >> 4, low = lane & 15;
  int rowbase = blockIdx.x * 64 + wv * 16;

  float4v acc[8];
#pragma unroll
  for (int t = 0; t < 8; t++) acc[t] = (float4v){0.f, 0.f, 0.f, 0.f};

#pragma unroll
  for (int k4 = 0; k4 < 4; k4++) {
    int kb = k4 * 32 + quad * 8;
    half8v af = *(const half8v*)&xt[(wv * 16 + low) * 136 + kb];
    half8v bf[8];
#pragma unroll
    for (int t = 0; t < 8; t++)
      bf[t] = *(const half8v*)&Wt[(t * 16 + low) * 136 + kb];
#pragma unroll
    for (int t = 0; t < 8; t++)
      acc[t] = __builtin_amdgcn_mfma_f32_16x16x32_f16(af, bf[t], acc[t], 0, 0, 0);
  }
  __syncthreads();   // all xt reads done before reuse as hst

#pragma unroll
  for (int t = 0; t < 8; t++)
#pragma unroll
    for (int r = 0; r < 4; r++)
      hst[wv][quad * 4 + r][t * 16 + low] = (_Float16)acc[t][r];
  __syncthreads();

  {
    int r = lane >> 2, part = lane & 3;
    int grow = rowbase + r;
    if (grow < N_NODES) {
      const float4* src = (const float4*)&hst[wv][r][part * 32];
      float4* dst = (float4*)(h + (size_t)grow * HC + part * 32);
#pragma unroll
      for (int i = 0; i < 4; i++) dst[i] = src[i];
    }
  }
  {
    int grow = rowbase + low;
    float ss = 0.f, dd = 0.f;
#pragma unroll
    for (int i = 0; i < 32; i++) {
      float hv = (float)hst[wv][low][quad * 32 + i];
      ss += hv * aS[quad * 32 + i];
      dd += hv * aD[quad * 32 + i];
    }
    if (grow < N_NODES) {
      asrc[grow * NHEAD + quad] = ss;
      adst[grow * NHEAD + quad] = dd;
    }
  }
}

// ---------------------------------------------------------------------------
// CSR build, counting-sorted by (dst, src_tile). Hierarchical scan (R16).
// ---------------------------------------------------------------------------
__global__ __launch_bounds__(256) void k_hist(
    const int* __restrict__ dst, const int* __restrict__ src,
    int* __restrict__ degT) {
  int e = blockIdx.x * 256 + threadIdx.x;
  if (e >= E_TOT) return;
  int d, s;
  if (e < E_EDGES) { d = dst[e]; s = src[e]; } else { d = s = e - E_EDGES; }
  int t = s / TILE_N;
  atomicAdd(&degT[d * NT + t], 1);
}

__global__ __launch_bounds__(256) void k_scanA(
    const int* __restrict__ degT, int* __restrict__ bsum) {
  __shared__ int ps[256];
  int tid = threadIdx.x, b = blockIdx.x;
  int base = b * 1024 + tid * 4;
  int s = 0;
#pragma unroll
  for (int i = 0; i < 4; i++) {
    int idx = base + i;
    if (idx < NSEG) s += degT[idx];
  }
  ps[tid] = s;
  __syncthreads();
  for (int off = 128; off > 0; off >>= 1) {
    if (tid < off) ps[tid] += ps[tid + off];
    __syncthreads();
  }
  if (tid == 0) bsum[b] = ps[0];
}

// scanB: exclusive scan of block sums (+ pooled zero + barrier area zero)
__global__ __launch_bounds__(256) void k_scanB(
    const int* __restrict__ bsum, int* __restrict__ boff,
    unsigned* __restrict__ pooled, int* __restrict__ pc) {
  __shared__ int ps[256];
  int tid = threadIdx.x;
  {
    uint4* p4 = (uint4*)pooled;
#pragma unroll
    for (int i = 0; i < 8; i++) p4[tid * 8 + i] = make_uint4(0u, 0u, 0u, 0u);
  }
  for (int i = tid; i < 3 * PC_PER_LAYER; i += 256) pc[i] = 0;
  int s = (tid < SCAN_BLOCKS) ? bsum[tid] : 0;
  ps[tid] = s;
  __syncthreads();
  for (int off = 1; off < 256; off <<= 1) {
    int v = (tid >= off) ? ps[tid - off] : 0;
    __syncthreads();
    ps[tid] += v;
    __syncthreads();
  }
  if (tid < SCAN_BLOCKS) boff[tid] = ps[tid] - s;  // exclusive
}

__global__ __launch_bounds__(256) void k_scanC(
    const int* __restrict__ degT, const int* __restrict__ boff,
    int* __restrict__ offT) {
  __shared__ int ps[256];
  int tid = threadIdx.x, b = blockIdx.x;
  int base = b * 1024 + tid * 4;
  int d[4];
  int s = 0;
#pragma unroll
  for (int i = 0; i < 4; i++) {
    int idx = base + i;
    d[i] = (idx < NSEG) ? degT[idx] : 0;
    s += d[i];
  }
  ps[tid] = s;
  __syncthreads();
  for (int off = 1; off < 256; off <<= 1) {
    int v = (tid >= off) ? ps[tid - off] : 0;
    __syncthreads();
    ps[tid] += v;
    __syncthreads();
  }
  int run = boff[b] + ps[tid] - s;
#pragma unroll
  for (int i = 0; i < 4; i++) {
    int idx = base + i;
    if (idx < NSEG) {
      offT[idx] = run;
      run += d[i];
      if (idx == NSEG - 1) offT[NSEG] = run;
    }
  }
}

__global__ __launch_bounds__(256) void k_scatter(
    const int* __restrict__ src, const int* __restrict__ dst,
    const int* __restrict__ offT, int* __restrict__ cntT,
    int* __restrict__ csr_src) {
  int e = blockIdx.x * 256 + threadIdx.x;
  if (e >= E_TOT) return;
  int s, d;
  if (e < E_EDGES) { s = src[e]; d = dst[e]; } else { s = d = e - E_EDGES; }
  int t = s / TILE_N;
  int pos = offT[d * NT + t] + atomicAdd(&cntT[d * NT + t], 1);
  csr_src[pos] = s;
}

#define BFLY_MAX4(m0, m1, m2, m3)                         \
  _Pragma("unroll") for (int off = 1; off < 64; off <<= 1) { \
    m0 = fmaxf(m0, __shfl_xor(m0, off));                  \
    m1 = fmaxf(m1, __shfl_xor(m1, off));                  \
    m2 = fmaxf(m2, __shfl_xor(m2, off));                  \
    m3 = fmaxf(m3, __shfl_xor(m3, off));                  \
  }
#define BFLY_SUM4(s0, s1, s2, s3)                         \
  _Pragma("unroll") for (int off = 1; off < 64; off <<= 1) { \
    s0 += __shfl_xor(s0, off);                            \
    s1 += __shfl_xor(s1, off);                            \
    s2 += __shfl_xor(s2, off);                            \
    s3 += __shfl_xor(s3, off);                            \
  }

// ---------------------------------------------------------------------------
// R22: R21 compute verbatim; hierarchical soft barrier (contention fix).
// ---------------------------------------------------------------------------
__global__ __launch_bounds__(256, 4) void k_aggr(
    const int* __restrict__ offT, const int* __restrict__ csr_src,
    const float* __restrict__ asrc, const float* __restrict__ adst,
    const __half* __restrict__ h, const float* __restrict__ bias,
    const int* __restrict__ batch, float* __restrict__ out_h,
    unsigned* __restrict__ pooled, int* __restrict__ pc, int do_pool) {
  __shared__ float2 axy[4][NPW][64];        // 26.6 KB accumulators
  __shared__ float mst[4][NPW][NHEAD][3];   // m, adh, 1/S
  __shared__ float w4e[4][64][4];
  __shared__ int   sve[4][64];
  __shared__ int   nke[4][64];
  __shared__ int   ok_s;
  int tid = threadIdx.x, wl = tid >> 6, lane = tid & 63;
  int wid = blockIdx.x * 4 + wl;
  int nodebase = wid * NPW;
  int head = lane >> 4;

  // ---- phase 0: softmax stats (no h traffic) — R6-proven ----
  for (int k = 0; k < NPW; k++) {
    int node = nodebase + k;
    if (node >= N_NODES) break;
    axy[wl][k][lane] = make_float2(0.f, 0.f);
    int lo = offT[node * NT], hi = offT[node * NT + NT];
    int deg = hi - lo;
    float4 ad4 = ((const float4*)adst)[node];
    float m0, m1, m2, m3, s0, s1, s2, s3;
    if (deg <= 64) {
      int j = lo + lane;
      bool valid = j < hi;
      int sv = valid ? csr_src[j] : 0;
      float4 a4 = ((const float4*)asrc)[sv];
      float e0 = valid ? lrelu(a4.x + ad4.x) : -1e30f;
      float e1 = valid ? lrelu(a4.y + ad4.y) : -1e30f;
      float e2 = valid ? lrelu(a4.z + ad4.z) : -1e30f;
      float e3 = valid ? lrelu(a4.w + ad4.w) : -1e30f;
      m0 = e0; m1 = e1; m2 = e2; m3 = e3;
      BFLY_MAX4(m0, m1, m2, m3)
      float w0 = expf(e0 - m0), w1 = expf(e1 - m1);
      float w2 = expf(e2 - m2), w3 = expf(e3 - m3);
      s0 = w0; s1 = w1; s2 = w2; s3 = w3;
      BFLY_SUM4(s0, s1, s2, s3)
    } else {
      float M0 = -1e30f, M1 = -1e30f, M2 = -1e30f, M3 = -1e30f;
      for (int c = lo; c < hi; c += 64) {
        int j = c + lane;
        bool valid = j < hi;
        int sv = valid ? csr_src[j] : 0;
        float4 a4 = ((const float4*)asrc)[sv];
        float e0 = valid ? lrelu(a4.x + ad4.x) : -1e30f;
        float e1 = valid ? lrelu(a4.y + ad4.y) : -1e30f;
        float e2 = valid ? lrelu(a4.z + ad4.z) : -1e30f;
        float e3 = valid ? lrelu(a4.w + ad4.w) : -1e30f;
        BFLY_MAX4(e0, e1, e2, e3)
        M0 = fmaxf(M0, e0); M1 = fmaxf(M1, e1);
        M2 = fmaxf(M2, e2); M3 = fmaxf(M3, e3);
      }
      float S0 = 0.f, S1 = 0.f, S2 = 0.f, S3 = 0.f;
      for (int c = lo; c < hi; c += 64) {
        int j = c + lane;
        bool valid = j < hi;
        int sv = valid ? csr_src[j] : 0;
        float4 a4 = ((const float4*)asrc)[sv];
        float e0 = valid ? lrelu(a4.x + ad4.x) : -1e30f;
        float e1 = valid ? lrelu(a4.y + ad4.y) : -1e30f;
        float e2 = valid ? lrelu(a4.z + ad4.z) : -1e30f;
        float e3 = valid ? lrelu(a4.w + ad4.w) : -1e30f;
        float w0 = expf(e0 - M0), w1 = expf(e1 - M1);
        float w2 = expf(e2 - M2), w3 = expf(e3 - M3);
        float t0 = w0, t1 = w1, t2 = w2, t3 = w3;
        BFLY_SUM4(t0, t1, t2, t3)
        S0 += t0; S1 += t1; S2 += t2; S3 += t3;
      }
      m0 = M0; m1 = M1; m2 = M2; m3 = M3;
      s0 = S0; s1 = S1; s2 = S2; s3 = S3;
    }
    if (lane < 4) {
      float mm = lane == 0 ? m0 : lane == 1 ? m1 : lane == 2 ? m2 : m3;
      float ss = lane == 0 ? s0 : lane == 1 ? s1 : lane == 2 ? s2 : s3;
      float ad = lane == 0 ? ad4.x : lane == 1 ? ad4.y : lane == 2 ? ad4.z : ad4.w;
      mst[wl][k][lane][0] = mm;
      mst[wl][k][lane][1] = ad;
      mst[wl][k][lane][2] = 1.f / ss;
    }
  }
  __syncthreads();   // publish mst/axy; align waves within block

  bool coh = true;
  // Hierarchical soft barrier (R22): group counter (128-way, 64B-separated)
  // -> top counter (8-way) -> per-group go flags. Bounded spins everywhere;
  // timeout -> coh=false (drift mode, correctness unaffected).
#define SOFT_BAR(idx)                                                        \
  {                                                                          \
    __syncthreads();                                                         \
    if (tid == 0) {                                                          \
      int ok = 1;                                                            \
      int* bb = pc + (idx) * BAR_STRIDE;                                     \
      int g = (int)(blockIdx.x & 7);                                         \
      int* cnt = bb + g * 16;                                                \
      int* flg = bb + 128 + g * 16;                                          \
      int v = __hip_atomic_fetch_add(cnt, 1, __ATOMIC_ACQ_REL,               \
                                     __HIP_MEMORY_SCOPE_AGENT) + 1;          \
      if (coh) {                                                             \
        if (v == NBLK / 8) {                                                 \
          int tv = __hip_atomic_fetch_add(bb + 192, 1, __ATOMIC_ACQ_REL,     \
                                          __HIP_MEMORY_SCOPE_AGENT) + 1;     \
          if (tv == 8) {                                                     \
            for (int q = 0; q < 8; q++)                                      \
              __hip_atomic_store(bb + 128 + q * 16, 1, __ATOMIC_RELEASE,     \
                                 __HIP_MEMORY_SCOPE_AGENT);                  \
          }                                                                  \
        }                                                                    \
        int it = 0;                                                          \
        while (__hip_atomic_load(flg, __ATOMIC_ACQUIRE,                      \
                                 __HIP_MEMORY_SCOPE_AGENT) == 0) {           \
          if (++it > 2000) { ok = 0; break; }                                \
          __builtin_amdgcn_s_sleep(4);                                       \
        }                                                                    \
      } else ok = 0;                                                         \
      ok_s = ok;                                                             \
    }                                                                        \
    __syncthreads();                                                         \
    coh = coh && (ok_s != 0);                                                \
  }

  SOFT_BAR(0)

#define CONSUME(P)                                                           \
  {                                                                          \
    int jj = 0;                                                              \
    for (; jj + 8 <= (P); jj += 8) {                                         \
      float2 hv[8]; float wv[8]; int nv[8];                                  \
      _Pragma("unroll")                                                      \
      for (int u = 0; u < 8; u++) {                                          \
        int iu = sve[wl][jj + u];                                            \
        wv[u] = w4e[wl][jj + u][head];                                       \
        nv[u] = nke[wl][jj + u];                                             \
        hv[u] = __half22float2(*(const __half2*)(h + (size_t)iu * HC + lane * 2)); \
      }                                                                      \
      _Pragma("unroll")                                                      \
      for (int u = 0; u < 8; u++) {                                          \
        float2 a = axy[wl][nv[u]][lane];                                     \
        a.x += wv[u] * hv[u].x;                                              \
        a.y += wv[u] * hv[u].y;                                              \
        axy[wl][nv[u]][lane] = a;                                            \
      }                                                                      \
    }                                                                        \
    for (; jj < (P); jj++) {                                                 \
      int iu = sve[wl][jj];                                                  \
      float wu = w4e[wl][jj][head];                                          \
      int nu = nke[wl][jj];                                                  \
      float2 hu = __half22float2(*(const __half2*)(h + (size_t)iu * HC + lane * 2)); \
      float2 a = axy[wl][nu][lane];                                          \
      a.x += wu * hu.x;                                                      \
      a.y += wu * hu.y;                                                      \
      axy[wl][nu][lane] = a;                                                 \
    }                                                                        \
  }

  // ---- tile phases: write-time-ownership stash + 8-deep consume ----
  for (int t = 0; t < NT; t++) {
    int pos = 0;
    for (int k = 0; k < NPW; k++) {
      int node = nodebase + k;
      if (node >= N_NODES) break;
      int s0 = offT[node * NT + t];
      int L  = offT[node * NT + t + 1] - s0;
      for (int c = 0; c < L; c += 64) {
        int n = (L - c < 64) ? (L - c) : 64;
        if (pos + n > 64) { CONSUME(pos); pos = 0; }
        if (lane < n) {
          int sv = csr_src[s0 + c + lane];
          sv = iclamp(sv, 0, N_NODES - 1);   // safety clamp (cheap)
          float4 a4 = ((const float4*)asrc)[sv];
          float w0 = expf(lrelu(a4.x + mst[wl][k][0][1]) - mst[wl][k][0][0]);
          float w1 = expf(lrelu(a4.y + mst[wl][k][1][1]) - mst[wl][k][1][0]);
          float w2 = expf(lrelu(a4.z + mst[wl][k][2][1]) - mst[wl][k][2][0]);
          float w3 = expf(lrelu(a4.w + mst[wl][k][3][1]) - mst[wl][k][3][0]);
          sve[wl][pos + lane] = sv;
          nke[wl][pos + lane] = k;
          *(float4*)&w4e[wl][pos + lane][0] = make_float4(w0, w1, w2, w3);
        }
        pos += n;
      }
    }
    CONSUME(pos);
    if (t < NT - 1) SOFT_BAR(1 + t)
  }
#undef CONSUME
#undef SOFT_BAR

  // ---- epilogue: normalize, bias, relu, store (+pool) — R6-proven ----
  float2 b = *(const float2*)(bias + lane * 2);
  for (int k = 0; k < NPW; k++) {
    int node = nodebase + k;
    if (node >= N_NODES) break;
    float rd = mst[wl][k][head][2];
    float vx = fmaxf(axy[wl][k][lane].x * rd + b.x, 0.f);
    float vy = fmaxf(axy[wl][k][lane].y * rd + b.y, 0.f);
    *(float2*)(out_h + (size_t)node * HC + lane * 2) = make_float2(vx, vy);
    if (do_pool) {
      int g = batch[node];
      unsigned* pp = pooled + g * HC + lane * 2;
      // post-relu values >= 0: bit compare == float compare; init 0 matches
      // the reference's where(isfinite, pooled, 0) empty-graph guard.
      atomicMax(pp + 0, __float_as_uint(vx));
      atomicMax(pp + 1, __float_as_uint(vy));
    }
  }
}

// final head: out[g] = (pooled[g] @ Wlin + blin) @ Wout + bout ; 1 block/graph
__global__ __launch_bounds__(256) void k_mlp(
    const float* __restrict__ pooled, const float* __restrict__ Wlin,
    const float* __restrict__ blin, const float* __restrict__ Wout,
    const float* __restrict__ bout, float* __restrict__ out) {
  __shared__ float p[HC];
  __shared__ float z[LIN];
  int g = blockIdx.x, tid = threadIdx.x;
  if (tid < HC) p[tid] = pooled[g * HC + tid];
  __syncthreads();
  float zv = blin[tid];
  for (int k = 0; k < HC; k++) zv += p[k] * Wlin[k * LIN + tid];
  z[tid] = zv;
  __syncthreads();
  if (tid < OUTC) {
    float o = bout[tid];
    for (int k = 0; k < LIN; k++) o += z[k] * Wout[k * OUTC + tid];
    out[g * OUTC + tid] = o;
  }
}

extern "C" void kernel_launch(void* const* d_in, const int* in_sizes, int n_in,
                              void* d_out, int out_size, void* d_ws, size_t ws_size,
                              hipStream_t stream) {
  const float* x     = (const float*)d_in[0];
  const int*   ei    = (const int*)d_in[1];
  const int*   batch = (const int*)d_in[2];
  const float* Wl[3] = {(const float*)d_in[3], (const float*)d_in[7], (const float*)d_in[11]};
  const float* As[3] = {(const float*)d_in[4], (const float*)d_in[8], (const float*)d_in[12]};
  const float* Ad[3] = {(const float*)d_in[5], (const float*)d_in[9], (const float*)d_in[13]};
  const float* Bi[3] = {(const float*)d_in[6], (const float*)d_in[10], (const float*)d_in[14]};
  const float* Wlin  = (const float*)d_in[15];
  const float* blin  = (const float*)d_in[16];
  const float* Wout  = (const float*)d_in[17];
  const float* bout  = (const float*)d_in[18];
  float* out = (float*)d_out;

  // workspace layout (float offsets)
  float* ws = (float*)d_ws;
  __half*   h       = (__half*)ws;                 // N*128 halves (3.2M fl)
  float*    nodeB   = ws + 3200000;                // N*128 fp32   (6.4M fl)
  float*    asrc    = ws + 9600000;                // N*4
  float*    adst    = ws + 9800000;                // N*4
  int*      degT    = (int*)(ws + 10000000);       // 250k (adjacent to cntT)
  int*      cntT    = (int*)(ws + 10250000);       // 250k
  int*      offT    = (int*)(ws + 10500000);       // 250001
  int*      csr_src = (int*)(ws + 10750004);       // E_TOT (+pad)
  unsigned* pooled  = (unsigned*)(ws + 11600008);  // 64*128
  int*      bsum    = (int*)(ws + 11608200);       // 245
  int*      boff    = (int*)(ws + 11608456);       // 245
  int*      pc      = (int*)(ws + 11608704);       // 3 * 1280 barrier ints

  const int* srcp = ei;
  const int* dstp = ei + E_EDGES;

  hipMemsetAsync(degT, 0, 2 * NSEG * sizeof(int), stream);  // degT + cntT

  // (dst, src_tile)-sorted CSR — built once, reused by all 3 layers
  k_hist<<<(E_TOT + 255) / 256, 256, 0, stream>>>(dstp, srcp, degT);
  k_scanA<<<SCAN_BLOCKS, 256, 0, stream>>>(degT, bsum);
  k_scanB<<<1, 256, 0, stream>>>(bsum, boff, pooled, pc);
  k_scanC<<<SCAN_BLOCKS, 256, 0, stream>>>(degT, boff, offT);
  k_scatter<<<(E_TOT + 255) / 256, 256, 0, stream>>>(srcp, dstp, offT, cntT, csr_src);

  const float* lin_in = x;
  for (int L = 0; L < 3; L++) {
    k_gemm_mfma<<<(N_NODES + 63) / 64, 256, 0, stream>>>(
        lin_in, Wl[L], As[L], Ad[L], h, asrc, adst);
    k_aggr<<<NBLK, 256, 0, stream>>>(
        offT, csr_src, asrc, adst, h, Bi[L], batch,
        nodeB, pooled, pc + L * PC_PER_LAYER, (L == 2) ? 1 : 0);
    lin_in = nodeB;
  }
  k_mlp<<<NG, 256, 0, stream>>>((const float*)pooled, Wlin, blin, Wout, bout, out);
}

// Round 12
// 2625.889 us; speedup vs baseline: 1.1924x; 1.0626x over previous
//
#include <hip/hip_runtime.h>
#include <hip/hip_fp16.h>
#include <hip/hip_cooperative_groups.h>
#include <math.h>

namespace cg = cooperative_groups;

#define N_NODES 50000
#define E_EDGES 800000
#define E_TOT   850000   // E + N self loops
#define HC 128
#define NHEAD 4
#define LIN 256
#define OUTC 10
#define NG 64
#define NEG_SLOPE 0.2f

// (dst, src-tile)-sorted CSR (R16). R23 = R21/R22 compute VERBATIM (passed
// twice, absmax 9.8e-4, FETCH 53MB) + hipLaunchCooperativeKernel grid.sync()
// replacing the soft barriers. R10/R11 showed the soft barriers never
// complete (each block burns its full spin timeout once -> the ~800us
// stall at VALUBusy 7-8%); cooperative launch guarantees co-residency and
// gives a real grid barrier.
#define NT 5
#define TILE_N 10000
#define NSEG (N_NODES * NT)     // 250000 (dst,tile) cells
#define SCAN_BLOCKS 245         // 245 * 1024 cells >= NSEG
#define NBLK 1024               // 4 blocks/CU x 256 CU (cooperative max fits)
#define NPW 13                  // consecutive nodes per wave: 4096*13 >= 50000

__device__ __forceinline__ float lrelu(float v) { return v > 0.f ? v : NEG_SLOPE * v; }
__device__ __forceinline__ int iclamp(int v, int lo, int hi) {
  return v < lo ? lo : (v > hi ? hi : v);
}

typedef _Float16 half8v __attribute__((ext_vector_type(8)));
typedef float    float4v __attribute__((ext_vector_type(4)));

// ---------------------------------------------------------------------------
// MFMA GEMM + attention logits (R18 A-staged version, -25us proven).
// ---------------------------------------------------------------------------
__global__ __launch_bounds__(256) void k_gemm_mfma(
    const float* __restrict__ x, const float* __restrict__ W,
    const float* __restrict__ a_s, const float* __restrict__ a_d,
    __half* __restrict__ h, float* __restrict__ asrc, float* __restrict__ adst) {
  __shared__ _Float16 Wt[128 * 136];       // W^T fp16, padded row stride 136
  __shared__ _Float16 xt[64 * 136];        // x-tile fp16 (later reused as hst)
  __shared__ float aS[HC], aD[HC];
  _Float16 (*hst)[16][136] = (_Float16 (*)[16][136])xt;  // epilogue alias
  int tid = threadIdx.x;
  if (tid < HC) { aS[tid] = a_s[tid]; aD[tid] = a_d[tid]; }
  for (int i = 0; i < 64; i++) {
    int idx = tid + i * 256;               // 16384 elements
    int k = idx >> 7, n = idx & 127;
    Wt[n * 136 + k] = (_Float16)W[idx];
  }
  {
    int rowbase0 = blockIdx.x * 64;
#pragma unroll
    for (int i = 0; i < 8; i++) {
      int idx = tid + i * 256;             // f4 index 0..2047
      int row = idx >> 5, c4 = idx & 31;
      int grow = rowbase0 + row;
      if (grow > N_NODES - 1) grow = N_NODES - 1;  // clamp; stores guarded
      float4 f4 = ((const float4*)x)[(size_t)grow * 32 + c4];
      _Float16* p = &xt[row * 136 + c4 * 4];
      p[0] = (_Float16)f4.x; p[1] = (_Float16)f4.y;
      p[2] = (_Float16)f4.z; p[3] = (_Float16)f4.w;
    }
  }
  __syncthreads();

  int wv = tid >> 6, lane = tid & 63;
  int quad = lane >> 4, low = lane & 15;
  int rowbase = blockIdx.x * 64 + wv * 16;

  float4v acc[8];
#pragma unroll
  for (int t = 0; t < 8; t++) acc[t] = (float4v){0.f, 0.f, 0.f, 0.f};

#pragma unroll
  for (int k4 = 0; k4 < 4; k4++) {
    int kb = k4 * 32 + quad * 8;
    half8v af = *(const half8v*)&xt[(wv * 16 + low) * 136 + kb];
    half8v bf[8];
#pragma unroll
    for (int t = 0; t < 8; t++)
      bf[t] = *(const half8v*)&Wt[(t * 16 + low) * 136 + kb];
#pragma unroll
    for (int t = 0; t < 8; t++)
      acc[t] = __builtin_amdgcn_mfma_f32_16x16x32_f16(af, bf[t], acc[t], 0, 0, 0);
  }
  __syncthreads();   // all xt reads done before reuse as hst

#pragma unroll
  for (int t = 0; t < 8; t++)
#pragma unroll
    for (int r = 0; r < 4; r++)
      hst[wv][quad * 4 + r][t * 16 + low] = (_Float16)acc[t][r];
  __syncthreads();

  {
    int r = lane >> 2, part = lane & 3;
    int grow = rowbase + r;
    if (grow < N_NODES) {
      const float4* src = (const float4*)&hst[wv][r][part * 32];
      float4* dst = (float4*)(h + (size_t)grow * HC + part * 32);
#pragma unroll
      for (int i = 0; i < 4; i++) dst[i] = src[i];
    }
  }
  {
    int grow = rowbase + low;
    float ss = 0.f, dd = 0.f;
#pragma unroll
    for (int i = 0; i < 32; i++) {
      float hv = (float)hst[wv][low][quad * 32 + i];
      ss += hv * aS[quad * 32 + i];
      dd += hv * aD[quad * 32 + i];
    }
    if (grow < N_NODES) {
      asrc[grow * NHEAD + quad] = ss;
      adst[grow * NHEAD + quad] = dd;
    }
  }
}

// ---------------------------------------------------------------------------
// CSR build, counting-sorted by (dst, src_tile). Hierarchical scan (R16).
// ---------------------------------------------------------------------------
__global__ __launch_bounds__(256) void k_hist(
    const int* __restrict__ dst, const int* __restrict__ src,
    int* __restrict__ degT) {
  int e = blockIdx.x * 256 + threadIdx.x;
  if (e >= E_TOT) return;
  int d, s;
  if (e < E_EDGES) { d = dst[e]; s = src[e]; } else { d = s = e - E_EDGES; }
  int t = s / TILE_N;
  atomicAdd(&degT[d * NT + t], 1);
}

__global__ __launch_bounds__(256) void k_scanA(
    const int* __restrict__ degT, int* __restrict__ bsum) {
  __shared__ int ps[256];
  int tid = threadIdx.x, b = blockIdx.x;
  int base = b * 1024 + tid * 4;
  int s = 0;
#pragma unroll
  for (int i = 0; i < 4; i++) {
    int idx = base + i;
    if (idx < NSEG) s += degT[idx];
  }
  ps[tid] = s;
  __syncthreads();
  for (int off = 128; off > 0; off >>= 1) {
    if (tid < off) ps[tid] += ps[tid + off];
    __syncthreads();
  }
  if (tid == 0) bsum[b] = ps[0];
}

// scanB: exclusive scan of the 245 block sums (+ pooled zeroing folded in)
__global__ __launch_bounds__(256) void k_scanB(
    const int* __restrict__ bsum, int* __restrict__ boff,
    unsigned* __restrict__ pooled) {
  __shared__ int ps[256];
  int tid = threadIdx.x;
  {
    uint4* p4 = (uint4*)pooled;
#pragma unroll
    for (int i = 0; i < 8; i++) p4[tid * 8 + i] = make_uint4(0u, 0u, 0u, 0u);
  }
  int s = (tid < SCAN_BLOCKS) ? bsum[tid] : 0;
  ps[tid] = s;
  __syncthreads();
  for (int off = 1; off < 256; off <<= 1) {
    int v = (tid >= off) ? ps[tid - off] : 0;
    __syncthreads();
    ps[tid] += v;
    __syncthreads();
  }
  if (tid < SCAN_BLOCKS) boff[tid] = ps[tid] - s;  // exclusive
}

__global__ __launch_bounds__(256) void k_scanC(
    const int* __restrict__ degT, const int* __restrict__ boff,
    int* __restrict__ offT) {
  __shared__ int ps[256];
  int tid = threadIdx.x, b = blockIdx.x;
  int base = b * 1024 + tid * 4;
  int d[4];
  int s = 0;
#pragma unroll
  for (int i = 0; i < 4; i++) {
    int idx = base + i;
    d[i] = (idx < NSEG) ? degT[idx] : 0;
    s += d[i];
  }
  ps[tid] = s;
  __syncthreads();
  for (int off = 1; off < 256; off <<= 1) {
    int v = (tid >= off) ? ps[tid - off] : 0;
    __syncthreads();
    ps[tid] += v;
    __syncthreads();
  }
  int run = boff[b] + ps[tid] - s;
#pragma unroll
  for (int i = 0; i < 4; i++) {
    int idx = base + i;
    if (idx < NSEG) {
      offT[idx] = run;
      run += d[i];
      if (idx == NSEG - 1) offT[NSEG] = run;
    }
  }
}

__global__ __launch_bounds__(256) void k_scatter(
    const int* __restrict__ src, const int* __restrict__ dst,
    const int* __restrict__ offT, int* __restrict__ cntT,
    int* __restrict__ csr_src) {
  int e = blockIdx.x * 256 + threadIdx.x;
  if (e >= E_TOT) return;
  int s, d;
  if (e < E_EDGES) { s = src[e]; d = dst[e]; } else { s = d = e - E_EDGES; }
  int t = s / TILE_N;
  int pos = offT[d * NT + t] + atomicAdd(&cntT[d * NT + t], 1);
  csr_src[pos] = s;
}

#define BFLY_MAX4(m0, m1, m2, m3)                         \
  _Pragma("unroll") for (int off = 1; off < 64; off <<= 1) { \
    m0 = fmaxf(m0, __shfl_xor(m0, off));                  \
    m1 = fmaxf(m1, __shfl_xor(m1, off));                  \
    m2 = fmaxf(m2, __shfl_xor(m2, off));                  \
    m3 = fmaxf(m3, __shfl_xor(m3, off));                  \
  }
#define BFLY_SUM4(s0, s1, s2, s3)                         \
  _Pragma("unroll") for (int off = 1; off < 64; off <<= 1) { \
    s0 += __shfl_xor(s0, off);                            \
    s1 += __shfl_xor(s1, off);                            \
    s2 += __shfl_xor(s2, off);                            \
    s3 += __shfl_xor(s3, off);                            \
  }

// ---------------------------------------------------------------------------
// R23: cooperative persistent aggr. R21 compute verbatim; grid.sync()
// between tile phases (real barrier; co-residency guaranteed by launch).
// ---------------------------------------------------------------------------
__global__ __launch_bounds__(256, 4) void k_aggr(
    const int* __restrict__ offT, const int* __restrict__ csr_src,
    const float* __restrict__ asrc, const float* __restrict__ adst,
    const __half* __restrict__ h, const float* __restrict__ bias,
    const int* __restrict__ batch, float* __restrict__ out_h,
    unsigned* __restrict__ pooled, int do_pool) {
  cg::grid_group grid = cg::this_grid();
  __shared__ float2 axy[4][NPW][64];        // 26.6 KB accumulators
  __shared__ float mst[4][NPW][NHEAD][3];   // m, adh, 1/S
  __shared__ float w4e[4][64][4];
  __shared__ int   sve[4][64];
  __shared__ int   nke[4][64];
  int tid = threadIdx.x, wl = tid >> 6, lane = tid & 63;
  int wid = blockIdx.x * 4 + wl;
  int nodebase = wid * NPW;
  int head = lane >> 4;

  // ---- phase 0: softmax stats (no h traffic) — R6-proven ----
  for (int k = 0; k < NPW; k++) {
    int node = nodebase + k;
    if (node >= N_NODES) break;
    axy[wl][k][lane] = make_float2(0.f, 0.f);
    int lo = offT[node * NT], hi = offT[node * NT + NT];
    int deg = hi - lo;
    float4 ad4 = ((const float4*)adst)[node];
    float m0, m1, m2, m3, s0, s1, s2, s3;
    if (deg <= 64) {
      int j = lo + lane;
      bool valid = j < hi;
      int sv = valid ? csr_src[j] : 0;
      float4 a4 = ((const float4*)asrc)[sv];
      float e0 = valid ? lrelu(a4.x + ad4.x) : -1e30f;
      float e1 = valid ? lrelu(a4.y + ad4.y) : -1e30f;
      float e2 = valid ? lrelu(a4.z + ad4.z) : -1e30f;
      float e3 = valid ? lrelu(a4.w + ad4.w) : -1e30f;
      m0 = e0; m1 = e1; m2 = e2; m3 = e3;
      BFLY_MAX4(m0, m1, m2, m3)
      float w0 = expf(e0 - m0), w1 = expf(e1 - m1);
      float w2 = expf(e2 - m2), w3 = expf(e3 - m3);
      s0 = w0; s1 = w1; s2 = w2; s3 = w3;
      BFLY_SUM4(s0, s1, s2, s3)
    } else {
      float M0 = -1e30f, M1 = -1e30f, M2 = -1e30f, M3 = -1e30f;
      for (int c = lo; c < hi; c += 64) {
        int j = c + lane;
        bool valid = j < hi;
        int sv = valid ? csr_src[j] : 0;
        float4 a4 = ((const float4*)asrc)[sv];
        float e0 = valid ? lrelu(a4.x + ad4.x) : -1e30f;
        float e1 = valid ? lrelu(a4.y + ad4.y) : -1e30f;
        float e2 = valid ? lrelu(a4.z + ad4.z) : -1e30f;
        float e3 = valid ? lrelu(a4.w + ad4.w) : -1e30f;
        BFLY_MAX4(e0, e1, e2, e3)
        M0 = fmaxf(M0, e0); M1 = fmaxf(M1, e1);
        M2 = fmaxf(M2, e2); M3 = fmaxf(M3, e3);
      }
      float S0 = 0.f, S1 = 0.f, S2 = 0.f, S3 = 0.f;
      for (int c = lo; c < hi; c += 64) {
        int j = c + lane;
        bool valid = j < hi;
        int sv = valid ? csr_src[j] : 0;
        float4 a4 = ((const float4*)asrc)[sv];
        float e0 = valid ? lrelu(a4.x + ad4.x) : -1e30f;
        float e1 = valid ? lrelu(a4.y + ad4.y) : -1e30f;
        float e2 = valid ? lrelu(a4.z + ad4.z) : -1e30f;
        float e3 = valid ? lrelu(a4.w + ad4.w) : -1e30f;
        float w0 = expf(e0 - M0), w1 = expf(e1 - M1);
        float w2 = expf(e2 - M2), w3 = expf(e3 - M3);
        float t0 = w0, t1 = w1, t2 = w2, t3 = w3;
        BFLY_SUM4(t0, t1, t2, t3)
        S0 += t0; S1 += t1; S2 += t2; S3 += t3;
      }
      m0 = M0; m1 = M1; m2 = M2; m3 = M3;
      s0 = S0; s1 = S1; s2 = S2; s3 = S3;
    }
    if (lane < 4) {
      float mm = lane == 0 ? m0 : lane == 1 ? m1 : lane == 2 ? m2 : m3;
      float ss = lane == 0 ? s0 : lane == 1 ? s1 : lane == 2 ? s2 : s3;
      float ad = lane == 0 ? ad4.x : lane == 1 ? ad4.y : lane == 2 ? ad4.z : ad4.w;
      mst[wl][k][lane][0] = mm;
      mst[wl][k][lane][1] = ad;
      mst[wl][k][lane][2] = 1.f / ss;
    }
  }

  grid.sync();   // align all waves on tile phase entry

#define CONSUME(P)                                                           \
  {                                                                          \
    int jj = 0;                                                              \
    for (; jj + 8 <= (P); jj += 8) {                                         \
      float2 hv[8]; float wv[8]; int nv[8];                                  \
      _Pragma("unroll")                                                      \
      for (int u = 0; u < 8; u++) {                                          \
        int iu = sve[wl][jj + u];                                            \
        wv[u] = w4e[wl][jj + u][head];                                       \
        nv[u] = nke[wl][jj + u];                                             \
        hv[u] = __half22float2(*(const __half2*)(h + (size_t)iu * HC + lane * 2)); \
      }                                                                      \
      _Pragma("unroll")                                                      \
      for (int u = 0; u < 8; u++) {                                          \
        float2 a = axy[wl][nv[u]][lane];                                     \
        a.x += wv[u] * hv[u].x;                                              \
        a.y += wv[u] * hv[u].y;                                              \
        axy[wl][nv[u]][lane] = a;                                            \
      }                                                                      \
    }                                                                        \
    for (; jj < (P); jj++) {                                                 \
      int iu = sve[wl][jj];                                                  \
      float wu = w4e[wl][jj][head];                                          \
      int nu = nke[wl][jj];                                                  \
      float2 hu = __half22float2(*(const __half2*)(h + (size_t)iu * HC + lane * 2)); \
      float2 a = axy[wl][nu][lane];                                          \
      a.x += wu * hu.x;                                                      \
      a.y += wu * hu.y;                                                      \
      axy[wl][nu][lane] = a;                                                 \
    }                                                                        \
  }

  // ---- tile phases: write-time-ownership stash + 8-deep consume ----
  for (int t = 0; t < NT; t++) {
    int pos = 0;
    for (int k = 0; k < NPW; k++) {
      int node = nodebase + k;
      if (node >= N_NODES) break;
      int s0 = offT[node * NT + t];
      int L  = offT[node * NT + t + 1] - s0;
      for (int c = 0; c < L; c += 64) {
        int n = (L - c < 64) ? (L - c) : 64;
        if (pos + n > 64) { CONSUME(pos); pos = 0; }
        if (lane < n) {
          int sv = csr_src[s0 + c + lane];
          sv = iclamp(sv, 0, N_NODES - 1);   // safety clamp (cheap)
          float4 a4 = ((const float4*)asrc)[sv];
          float w0 = expf(lrelu(a4.x + mst[wl][k][0][1]) - mst[wl][k][0][0]);
          float w1 = expf(lrelu(a4.y + mst[wl][k][1][1]) - mst[wl][k][1][0]);
          float w2 = expf(lrelu(a4.z + mst[wl][k][2][1]) - mst[wl][k][2][0]);
          float w3 = expf(lrelu(a4.w + mst[wl][k][3][1]) - mst[wl][k][3][0]);
          sve[wl][pos + lane] = sv;
          nke[wl][pos + lane] = k;
          *(float4*)&w4e[wl][pos + lane][0] = make_float4(w0, w1, w2, w3);
        }
        pos += n;
      }
    }
    CONSUME(pos);
    if (t < NT - 1) grid.sync();
  }
#undef CONSUME

  // ---- epilogue: normalize, bias, relu, store (+pool) — R6-proven ----
  float2 b = *(const float2*)(bias + lane * 2);
  for (int k = 0; k < NPW; k++) {
    int node = nodebase + k;
    if (node >= N_NODES) break;
    float rd = mst[wl][k][head][2];
    float vx = fmaxf(axy[wl][k][lane].x * rd + b.x, 0.f);
    float vy = fmaxf(axy[wl][k][lane].y * rd + b.y, 0.f);
    *(float2*)(out_h + (size_t)node * HC + lane * 2) = make_float2(vx, vy);
    if (do_pool) {
      int g = batch[node];
      unsigned* pp = pooled + g * HC + lane * 2;
      // post-relu values >= 0: bit compare == float compare; init 0 matches
      // the reference's where(isfinite, pooled, 0) empty-graph guard.
      atomicMax(pp + 0, __float_as_uint(vx));
      atomicMax(pp + 1, __float_as_uint(vy));
    }
  }
}

// final head: out[g] = (pooled[g] @ Wlin + blin) @ Wout + bout ; 1 block/graph
__global__ __launch_bounds__(256) void k_mlp(
    const float* __restrict__ pooled, const float* __restrict__ Wlin,
    const float* __restrict__ blin, const float* __restrict__ Wout,
    const float* __restrict__ bout, float* __restrict__ out) {
  __shared__ float p[HC];
  __shared__ float z[LIN];
  int g = blockIdx.x, tid = threadIdx.x;
  if (tid < HC) p[tid] = pooled[g * HC + tid];
  __syncthreads();
  float zv = blin[tid];
  for (int k = 0; k < HC; k++) zv += p[k] * Wlin[k * LIN + tid];
  z[tid] = zv;
  __syncthreads();
  if (tid < OUTC) {
    float o = bout[tid];
    for (int k = 0; k < LIN; k++) o += z[k] * Wout[k * OUTC + tid];
    out[g * OUTC + tid] = o;
  }
}

extern "C" void kernel_launch(void* const* d_in, const int* in_sizes, int n_in,
                              void* d_out, int out_size, void* d_ws, size_t ws_size,
                              hipStream_t stream) {
  const float* x     = (const float*)d_in[0];
  const int*   ei    = (const int*)d_in[1];
  const int*   batch = (const int*)d_in[2];
  const float* Wl[3] = {(const float*)d_in[3], (const float*)d_in[7], (const float*)d_in[11]};
  const float* As[3] = {(const float*)d_in[4], (const float*)d_in[8], (const float*)d_in[12]};
  const float* Ad[3] = {(const float*)d_in[5], (const float*)d_in[9], (const float*)d_in[13]};
  const float* Bi[3] = {(const float*)d_in[6], (const float*)d_in[10], (const float*)d_in[14]};
  const float* Wlin  = (const float*)d_in[15];
  const float* blin  = (const float*)d_in[16];
  const float* Wout  = (const float*)d_in[17];
  const float* bout  = (const float*)d_in[18];
  float* out = (float*)d_out;

  // workspace layout (float offsets)
  float* ws = (float*)d_ws;
  __half*   h       = (__half*)ws;                 // N*128 halves (3.2M fl)
  float*    nodeB   = ws + 3200000;                // N*128 fp32   (6.4M fl)
  float*    asrc    = ws + 9600000;                // N*4
  float*    adst    = ws + 9800000;                // N*4
  int*      degT    = (int*)(ws + 10000000);       // 250k (adjacent to cntT)
  int*      cntT    = (int*)(ws + 10250000);       // 250k
  int*      offT    = (int*)(ws + 10500000);       // 250001
  int*      csr_src = (int*)(ws + 10750004);       // E_TOT (+pad)
  unsigned* pooled  = (unsigned*)(ws + 11600008);  // 64*128
  int*      bsum    = (int*)(ws + 11608200);       // 245
  int*      boff    = (int*)(ws + 11608456);       // 245

  const int* srcp = ei;
  const int* dstp = ei + E_EDGES;

  hipMemsetAsync(degT, 0, 2 * NSEG * sizeof(int), stream);  // degT + cntT

  // (dst, src_tile)-sorted CSR — built once, reused by all 3 layers
  k_hist<<<(E_TOT + 255) / 256, 256, 0, stream>>>(dstp, srcp, degT);
  k_scanA<<<SCAN_BLOCKS, 256, 0, stream>>>(degT, bsum);
  k_scanB<<<1, 256, 0, stream>>>(bsum, boff, pooled);
  k_scanC<<<SCAN_BLOCKS, 256, 0, stream>>>(degT, boff, offT);
  k_scatter<<<(E_TOT + 255) / 256, 256, 0, stream>>>(srcp, dstp, offT, cntT, csr_src);

  const float* lin_in = x;
  for (int L = 0; L < 3; L++) {
    k_gemm_mfma<<<(N_NODES + 63) / 64, 256, 0, stream>>>(
        lin_in, Wl[L], As[L], Ad[L], h, asrc, adst);
    {
      const int* a_offT = offT;
      const int* a_csr  = csr_src;
      const float* a_as = asrc;
      const float* a_ad = adst;
      const __half* a_h = h;
      const float* a_bi = Bi[L];
      const int* a_ba   = batch;
      float* a_out      = nodeB;
      unsigned* a_pool  = pooled;
      int a_dp          = (L == 2) ? 1 : 0;
      void* kargs[] = {(void*)&a_offT, (void*)&a_csr, (void*)&a_as,
                       (void*)&a_ad,   (void*)&a_h,   (void*)&a_bi,
                       (void*)&a_ba,   (void*)&a_out, (void*)&a_pool,
                       (void*)&a_dp};
      hipLaunchCooperativeKernel((const void*)k_aggr, dim3(NBLK), dim3(256),
                                 kargs, 0, stream);
    }
    lin_in = nodeB;
  }
  k_mlp<<<NG, 256, 0, stream>>>((const float*)pooled, Wlin, blin, Wout, bout, out);
}

// Round 13
// 474.683 us; speedup vs baseline: 6.5964x; 5.5319x over previous
//
#include <hip/hip_runtime.h>
#include <hip/hip_fp16.h>
#include <math.h>

#define N_NODES 50000
#define E_EDGES 800000
#define E_TOT   850000   // E + N self loops
#define HC 128
#define NHEAD 4
#define LIN 256
#define OUTC 10
#define NG 64
#define NEG_SLOPE 0.2f

// (dst, src-tile)-sorted CSR (R16): edges of each node contiguous,
// tile-ordered; V_old aggr consumes [offT[n*NT], offT[(n+1)*NT]) unchanged.
// R24 = R7 (best, 483us) + rank-from-hist CSR (scatter loses its atomic
// pass; cntT deleted). Persistent/tiled track CLOSED after R6,R8-R12: tile
// segments avg 3.4 edges -> serialized stash chains cost more than the
// FETCH 99->53GB saving returns. V_old one-wave-per-node lane-parallel
// aggr is the proven structure; aggr is at the MSHR x latency floor
// (850k rows x 4 lines / 256 CU / 32 MSHR x ~850cy ~= 140us/layer).
#define NT 5
#define TILE_N 10000
#define NSEG (N_NODES * NT)     // 250000 (dst,tile) cells
#define SCAN_BLOCKS 245         // 245 * 1024 cells >= NSEG

__device__ __forceinline__ float lrelu(float v) { return v > 0.f ? v : NEG_SLOPE * v; }

typedef _Float16 half8v __attribute__((ext_vector_type(8)));
typedef float    float4v __attribute__((ext_vector_type(4)));

// ---------------------------------------------------------------------------
// MFMA GEMM + attention logits (R18 A-staged version, -25us proven).
// ---------------------------------------------------------------------------
__global__ __launch_bounds__(256) void k_gemm_mfma(
    const float* __restrict__ x, const float* __restrict__ W,
    const float* __restrict__ a_s, const float* __restrict__ a_d,
    __half* __restrict__ h, float* __restrict__ asrc, float* __restrict__ adst) {
  __shared__ _Float16 Wt[128 * 136];       // W^T fp16, padded row stride 136
  __shared__ _Float16 xt[64 * 136];        // x-tile fp16 (later reused as hst)
  __shared__ float aS[HC], aD[HC];
  _Float16 (*hst)[16][136] = (_Float16 (*)[16][136])xt;  // epilogue alias
  int tid = threadIdx.x;
  if (tid < HC) { aS[tid] = a_s[tid]; aD[tid] = a_d[tid]; }
  for (int i = 0; i < 64; i++) {
    int idx = tid + i * 256;               // 16384 elements
    int k = idx >> 7, n = idx & 127;
    Wt[n * 136 + k] = (_Float16)W[idx];
  }
  {
    int rowbase0 = blockIdx.x * 64;
#pragma unroll
    for (int i = 0; i < 8; i++) {
      int idx = tid + i * 256;             // f4 index 0..2047
      int row = idx >> 5, c4 = idx & 31;
      int grow = rowbase0 + row;
      if (grow > N_NODES - 1) grow = N_NODES - 1;  // clamp; stores guarded
      float4 f4 = ((const float4*)x)[(size_t)grow * 32 + c4];
      _Float16* p = &xt[row * 136 + c4 * 4];
      p[0] = (_Float16)f4.x; p[1] = (_Float16)f4.y;
      p[2] = (_Float16)f4.z; p[3] = (_Float16)f4.w;
    }
  }
  __syncthreads();

  int wv = tid >> 6, lane = tid & 63;
  int quad = lane >> 4, low = lane & 15;
  int rowbase = blockIdx.x * 64 + wv * 16;

  float4v acc[8];
#pragma unroll
  for (int t = 0; t < 8; t++) acc[t] = (float4v){0.f, 0.f, 0.f, 0.f};

#pragma unroll
  for (int k4 = 0; k4 < 4; k4++) {
    int kb = k4 * 32 + quad * 8;
    half8v af = *(const half8v*)&xt[(wv * 16 + low) * 136 + kb];
    half8v bf[8];
#pragma unroll
    for (int t = 0; t < 8; t++)
      bf[t] = *(const half8v*)&Wt[(t * 16 + low) * 136 + kb];
#pragma unroll
    for (int t = 0; t < 8; t++)
      acc[t] = __builtin_amdgcn_mfma_f32_16x16x32_f16(af, bf[t], acc[t], 0, 0, 0);
  }
  __syncthreads();   // all xt reads done before reuse as hst

#pragma unroll
  for (int t = 0; t < 8; t++)
#pragma unroll
    for (int r = 0; r < 4; r++)
      hst[wv][quad * 4 + r][t * 16 + low] = (_Float16)acc[t][r];
  __syncthreads();

  {
    int r = lane >> 2, part = lane & 3;
    int grow = rowbase + r;
    if (grow < N_NODES) {
      const float4* src = (const float4*)&hst[wv][r][part * 32];
      float4* dst = (float4*)(h + (size_t)grow * HC + part * 32);
#pragma unroll
      for (int i = 0; i < 4; i++) dst[i] = src[i];
    }
  }
  {
    int grow = rowbase + low;
    float ss = 0.f, dd = 0.f;
#pragma unroll
    for (int i = 0; i < 32; i++) {
      float hv = (float)hst[wv][low][quad * 32 + i];
      ss += hv * aS[quad * 32 + i];
      dd += hv * aD[quad * 32 + i];
    }
    if (grow < N_NODES) {
      asrc[grow * NHEAD + quad] = ss;
      adst[grow * NHEAD + quad] = dd;
    }
  }
}

// ---------------------------------------------------------------------------
// CSR build, counting-sorted by (dst, src_tile). Hierarchical scan (R16).
// R24: k_hist records within-cell rank (atomicAdd return) -> k_scatter needs
// no second atomic pass and cntT is gone.
// ---------------------------------------------------------------------------
__global__ __launch_bounds__(256) void k_hist(
    const int* __restrict__ dst, const int* __restrict__ src,
    int* __restrict__ degT, int* __restrict__ rank) {
  int e = blockIdx.x * 256 + threadIdx.x;
  if (e >= E_TOT) return;
  int d, s;
  if (e < E_EDGES) { d = dst[e]; s = src[e]; } else { d = s = e - E_EDGES; }
  int t = s / TILE_N;
  rank[e] = atomicAdd(&degT[d * NT + t], 1);
}

__global__ __launch_bounds__(256) void k_scanA(
    const int* __restrict__ degT, int* __restrict__ bsum) {
  __shared__ int ps[256];
  int tid = threadIdx.x, b = blockIdx.x;
  int base = b * 1024 + tid * 4;
  int s = 0;
#pragma unroll
  for (int i = 0; i < 4; i++) {
    int idx = base + i;
    if (idx < NSEG) s += degT[idx];
  }
  ps[tid] = s;
  __syncthreads();
  for (int off = 128; off > 0; off >>= 1) {
    if (tid < off) ps[tid] += ps[tid + off];
    __syncthreads();
  }
  if (tid == 0) bsum[b] = ps[0];
}

// scanB: exclusive scan of the 245 block sums (+ pooled zeroing folded in)
__global__ __launch_bounds__(256) void k_scanB(
    const int* __restrict__ bsum, int* __restrict__ boff,
    unsigned* __restrict__ pooled) {
  __shared__ int ps[256];
  int tid = threadIdx.x;
  {
    uint4* p4 = (uint4*)pooled;
#pragma unroll
    for (int i = 0; i < 8; i++) p4[tid * 8 + i] = make_uint4(0u, 0u, 0u, 0u);
  }
  int s = (tid < SCAN_BLOCKS) ? bsum[tid] : 0;
  ps[tid] = s;
  __syncthreads();
  for (int off = 1; off < 256; off <<= 1) {
    int v = (tid >= off) ? ps[tid - off] : 0;
    __syncthreads();
    ps[tid] += v;
    __syncthreads();
  }
  if (tid < SCAN_BLOCKS) boff[tid] = ps[tid] - s;  // exclusive
}

__global__ __launch_bounds__(256) void k_scanC(
    const int* __restrict__ degT, const int* __restrict__ boff,
    int* __restrict__ offT) {
  __shared__ int ps[256];
  int tid = threadIdx.x, b = blockIdx.x;
  int base = b * 1024 + tid * 4;
  int d[4];
  int s = 0;
#pragma unroll
  for (int i = 0; i < 4; i++) {
    int idx = base + i;
    d[i] = (idx < NSEG) ? degT[idx] : 0;
    s += d[i];
  }
  ps[tid] = s;
  __syncthreads();
  for (int off = 1; off < 256; off <<= 1) {
    int v = (tid >= off) ? ps[tid - off] : 0;
    __syncthreads();
    ps[tid] += v;
    __syncthreads();
  }
  int run = boff[b] + ps[tid] - s;
#pragma unroll
  for (int i = 0; i < 4; i++) {
    int idx = base + i;
    if (idx < NSEG) {
      offT[idx] = run;
      run += d[i];
      if (idx == NSEG - 1) offT[NSEG] = run;
    }
  }
}

__global__ __launch_bounds__(256) void k_scatter(
    const int* __restrict__ src, const int* __restrict__ dst,
    const int* __restrict__ offT, const int* __restrict__ rank,
    int* __restrict__ csr_src) {
  int e = blockIdx.x * 256 + threadIdx.x;
  if (e >= E_TOT) return;
  int s, d;
  if (e < E_EDGES) { s = src[e]; d = dst[e]; } else { s = d = e - E_EDGES; }
  int t = s / TILE_N;
  csr_src[offT[d * NT + t] + rank[e]] = s;
}

#define BFLY_MAX4(m0, m1, m2, m3)                         \
  _Pragma("unroll") for (int off = 1; off < 64; off <<= 1) { \
    m0 = fmaxf(m0, __shfl_xor(m0, off));                  \
    m1 = fmaxf(m1, __shfl_xor(m1, off));                  \
    m2 = fmaxf(m2, __shfl_xor(m2, off));                  \
    m3 = fmaxf(m3, __shfl_xor(m3, off));                  \
  }
#define BFLY_SUM4(s0, s1, s2, s3)                         \
  _Pragma("unroll") for (int off = 1; off < 64; off <<= 1) { \
    s0 += __shfl_xor(s0, off);                            \
    s1 += __shfl_xor(s1, off);                            \
    s2 += __shfl_xor(s2, off);                            \
    s3 += __shfl_xor(s3, off);                            \
  }

// ---------------------------------------------------------------------------
// Fused softmax + aggregation — V_old structure, verbatim (best: R7=483us).
// One wave per dst node; lane owns 2 feats; head = lane/16.
// LAW (R5/R7/R10, re-confirmed R13): every gather instruction's 64 lanes
// cover exactly ONE contiguous h-row span.
// At the MSHR x latency floor: 850k rows x 4 lines /256CU /32 MSHR x ~850cy
// ~= 140us/layer; timed ~134. Structural-change history: R12/13 quad-row
// 190us; R14 async-LDS 200us; R15 recompute 280us; R17/R21/R23 persistent
// tiled 825-1450us. This structure wins.
// ---------------------------------------------------------------------------
__global__ __launch_bounds__(256) void k_aggr(
    const int* __restrict__ offT, const int* __restrict__ csr_src,
    const float* __restrict__ asrc, const float* __restrict__ adst,
    const __half* __restrict__ h, const float* __restrict__ bias,
    const int* __restrict__ batch, float* __restrict__ out_h,
    unsigned* __restrict__ pooled, int do_pool) {
  __shared__ int   sv_lds[4][64];
  __shared__ float w_lds[4][64][4];
  int gid = blockIdx.x * 256 + threadIdx.x;
  int node = gid >> 6, lane = gid & 63, wl = threadIdx.x >> 6;
  if (node >= N_NODES) return;
  int head = lane >> 4;
  int lo = offT[node * NT], hi = offT[node * NT + NT];
  int deg = hi - lo;
  float4 ad4 = ((const float4*)adst)[node];  // broadcast
  float ax = 0.f, ay = 0.f;
  float S;

  if (deg <= 64) {
    int j = lo + lane;
    int sv = (j < hi) ? csr_src[j] : 0;
    float4 a4 = ((const float4*)asrc)[sv];
    bool valid = (j < hi);
    float e0 = valid ? lrelu(a4.x + ad4.x) : -1e30f;
    float e1 = valid ? lrelu(a4.y + ad4.y) : -1e30f;
    float e2 = valid ? lrelu(a4.z + ad4.z) : -1e30f;
    float e3 = valid ? lrelu(a4.w + ad4.w) : -1e30f;
    float m0 = e0, m1 = e1, m2 = e2, m3 = e3;
    BFLY_MAX4(m0, m1, m2, m3)
    float w0 = expf(e0 - m0), w1 = expf(e1 - m1);
    float w2 = expf(e2 - m2), w3 = expf(e3 - m3);  // invalid lanes -> 0
    float s0 = w0, s1 = w1, s2 = w2, s3 = w3;
    BFLY_SUM4(s0, s1, s2, s3)
    sv_lds[wl][lane] = sv;
    *(float4*)&w_lds[wl][lane][0] = make_float4(w0, w1, w2, w3);
    S = (head == 0) ? s0 : (head == 1) ? s1 : (head == 2) ? s2 : s3;
    int jj = 0;
    for (; jj + 8 <= deg; jj += 8) {
      int i0 = sv_lds[wl][jj + 0], i1 = sv_lds[wl][jj + 1];
      int i2 = sv_lds[wl][jj + 2], i3 = sv_lds[wl][jj + 3];
      int i4 = sv_lds[wl][jj + 4], i5 = sv_lds[wl][jj + 5];
      int i6 = sv_lds[wl][jj + 6], i7 = sv_lds[wl][jj + 7];
      float wA = w_lds[wl][jj + 0][head], wB = w_lds[wl][jj + 1][head];
      float wC = w_lds[wl][jj + 2][head], wD = w_lds[wl][jj + 3][head];
      float wE = w_lds[wl][jj + 4][head], wF = w_lds[wl][jj + 5][head];
      float wG = w_lds[wl][jj + 6][head], wH = w_lds[wl][jj + 7][head];
      float2 h0 = __half22float2(*(const __half2*)(h + (size_t)i0 * HC + lane * 2));
      float2 h1 = __half22float2(*(const __half2*)(h + (size_t)i1 * HC + lane * 2));
      float2 h2 = __half22float2(*(const __half2*)(h + (size_t)i2 * HC + lane * 2));
      float2 h3 = __half22float2(*(const __half2*)(h + (size_t)i3 * HC + lane * 2));
      float2 h4 = __half22float2(*(const __half2*)(h + (size_t)i4 * HC + lane * 2));
      float2 h5 = __half22float2(*(const __half2*)(h + (size_t)i5 * HC + lane * 2));
      float2 h6 = __half22float2(*(const __half2*)(h + (size_t)i6 * HC + lane * 2));
      float2 h7 = __half22float2(*(const __half2*)(h + (size_t)i7 * HC + lane * 2));
      ax += wA * h0.x; ay += wA * h0.y;
      ax += wB * h1.x; ay += wB * h1.y;
      ax += wC * h2.x; ay += wC * h2.y;
      ax += wD * h3.x; ay += wD * h3.y;
      ax += wE * h4.x; ay += wE * h4.y;
      ax += wF * h5.x; ay += wF * h5.y;
      ax += wG * h6.x; ay += wG * h6.y;
      ax += wH * h7.x; ay += wH * h7.y;
    }
    for (; jj + 4 <= deg; jj += 4) {
      int i0 = sv_lds[wl][jj + 0], i1 = sv_lds[wl][jj + 1];
      int i2 = sv_lds[wl][jj + 2], i3 = sv_lds[wl][jj + 3];
      float wA = w_lds[wl][jj + 0][head], wB = w_lds[wl][jj + 1][head];
      float wC = w_lds[wl][jj + 2][head], wD = w_lds[wl][jj + 3][head];
      float2 h0 = __half22float2(*(const __half2*)(h + (size_t)i0 * HC + lane * 2));
      float2 h1 = __half22float2(*(const __half2*)(h + (size_t)i1 * HC + lane * 2));
      float2 h2 = __half22float2(*(const __half2*)(h + (size_t)i2 * HC + lane * 2));
      float2 h3 = __half22float2(*(const __half2*)(h + (size_t)i3 * HC + lane * 2));
      ax += wA * h0.x; ay += wA * h0.y;
      ax += wB * h1.x; ay += wB * h1.y;
      ax += wC * h2.x; ay += wC * h2.y;
      ax += wD * h3.x; ay += wD * h3.y;
    }
    for (; jj < deg; jj++) {
      int i0 = sv_lds[wl][jj];
      float wA = w_lds[wl][jj][head];
      float2 h0 = __half22float2(*(const __half2*)(h + (size_t)i0 * HC + lane * 2));
      ax += wA * h0.x; ay += wA * h0.y;
    }
  } else {
    // rare generic path (deg > 64): chunked two-pass
    float M0 = -1e30f, M1 = -1e30f, M2 = -1e30f, M3 = -1e30f;
    for (int c = lo; c < hi; c += 64) {
      int j = c + lane;
      int sv = (j < hi) ? csr_src[j] : 0;
      float4 a4 = ((const float4*)asrc)[sv];
      bool valid = (j < hi);
      float e0 = valid ? lrelu(a4.x + ad4.x) : -1e30f;
      float e1 = valid ? lrelu(a4.y + ad4.y) : -1e30f;
      float e2 = valid ? lrelu(a4.z + ad4.z) : -1e30f;
      float e3 = valid ? lrelu(a4.w + ad4.w) : -1e30f;
      BFLY_MAX4(e0, e1, e2, e3)
      M0 = fmaxf(M0, e0); M1 = fmaxf(M1, e1);
      M2 = fmaxf(M2, e2); M3 = fmaxf(M3, e3);
    }
    float S0 = 0.f, S1 = 0.f, S2 = 0.f, S3 = 0.f;
    for (int c = lo; c < hi; c += 64) {
      int j = c + lane;
      int sv = (j < hi) ? csr_src[j] : 0;
      float4 a4 = ((const float4*)asrc)[sv];
      bool valid = (j < hi);
      float e0 = valid ? lrelu(a4.x + ad4.x) : -1e30f;
      float e1 = valid ? lrelu(a4.y + ad4.y) : -1e30f;
      float e2 = valid ? lrelu(a4.z + ad4.z) : -1e30f;
      float e3 = valid ? lrelu(a4.w + ad4.w) : -1e30f;
      float w0 = expf(e0 - M0), w1 = expf(e1 - M1);
      float w2 = expf(e2 - M2), w3 = expf(e3 - M3);
      float s0 = w0, s1 = w1, s2 = w2, s3 = w3;
      BFLY_SUM4(s0, s1, s2, s3)
      S0 += s0; S1 += s1; S2 += s2; S3 += s3;
      sv_lds[wl][lane] = sv;
      *(float4*)&w_lds[wl][lane][0] = make_float4(w0, w1, w2, w3);
      int cnt = (hi - c < 64) ? (hi - c) : 64;
      int jj = 0;
      for (; jj + 4 <= cnt; jj += 4) {
        int i0 = sv_lds[wl][jj + 0], i1 = sv_lds[wl][jj + 1];
        int i2 = sv_lds[wl][jj + 2], i3 = sv_lds[wl][jj + 3];
        float wA = w_lds[wl][jj + 0][head], wB = w_lds[wl][jj + 1][head];
        float wC = w_lds[wl][jj + 2][head], wD = w_lds[wl][jj + 3][head];
        float2 h0 = __half22float2(*(const __half2*)(h + (size_t)i0 * HC + lane * 2));
        float2 h1 = __half22float2(*(const __half2*)(h + (size_t)i1 * HC + lane * 2));
        float2 h2 = __half22float2(*(const __half2*)(h + (size_t)i2 * HC + lane * 2));
        float2 h3 = __half22float2(*(const __half2*)(h + (size_t)i3 * HC + lane * 2));
        ax += wA * h0.x; ay += wA * h0.y;
        ax += wB * h1.x; ay += wB * h1.y;
        ax += wC * h2.x; ay += wC * h2.y;
        ax += wD * h3.x; ay += wD * h3.y;
      }
      for (; jj < cnt; jj++) {
        int i0 = sv_lds[wl][jj];
        float wA = w_lds[wl][jj][head];
        float2 h0 = __half22float2(*(const __half2*)(h + (size_t)i0 * HC + lane * 2));
        ax += wA * h0.x; ay += wA * h0.y;
      }
    }
    S = (head == 0) ? S0 : (head == 1) ? S1 : (head == 2) ? S2 : S3;
  }

  float rden = 1.f / S;
  float2 b = *(const float2*)(bias + lane * 2);
  float vx = fmaxf(ax * rden + b.x, 0.f);
  float vy = fmaxf(ay * rden + b.y, 0.f);
  *(float2*)(out_h + (size_t)node * HC + lane * 2) = make_float2(vx, vy);
  if (do_pool) {
    int g = batch[node];
    unsigned* pp = pooled + g * HC + lane * 2;
    // post-relu values >= 0: bit compare == float compare; init 0 matches the
    // reference's where(isfinite, pooled, 0) empty-graph guard.
    atomicMax(pp + 0, __float_as_uint(vx));
    atomicMax(pp + 1, __float_as_uint(vy));
  }
}

// final head: out[g] = (pooled[g] @ Wlin + blin) @ Wout + bout ; 1 block/graph
__global__ __launch_bounds__(256) void k_mlp(
    const float* __restrict__ pooled, const float* __restrict__ Wlin,
    const float* __restrict__ blin, const float* __restrict__ Wout,
    const float* __restrict__ bout, float* __restrict__ out) {
  __shared__ float p[HC];
  __shared__ float z[LIN];
  int g = blockIdx.x, tid = threadIdx.x;
  if (tid < HC) p[tid] = pooled[g * HC + tid];
  __syncthreads();
  float zv = blin[tid];
  for (int k = 0; k < HC; k++) zv += p[k] * Wlin[k * LIN + tid];
  z[tid] = zv;
  __syncthreads();
  if (tid < OUTC) {
    float o = bout[tid];
    for (int k = 0; k < LIN; k++) o += z[k] * Wout[k * OUTC + tid];
    out[g * OUTC + tid] = o;
  }
}

extern "C" void kernel_launch(void* const* d_in, const int* in_sizes, int n_in,
                              void* d_out, int out_size, void* d_ws, size_t ws_size,
                              hipStream_t stream) {
  const float* x     = (const float*)d_in[0];
  const int*   ei    = (const int*)d_in[1];
  const int*   batch = (const int*)d_in[2];
  const float* Wl[3] = {(const float*)d_in[3], (const float*)d_in[7], (const float*)d_in[11]};
  const float* As[3] = {(const float*)d_in[4], (const float*)d_in[8], (const float*)d_in[12]};
  const float* Ad[3] = {(const float*)d_in[5], (const float*)d_in[9], (const float*)d_in[13]};
  const float* Bi[3] = {(const float*)d_in[6], (const float*)d_in[10], (const float*)d_in[14]};
  const float* Wlin  = (const float*)d_in[15];
  const float* blin  = (const float*)d_in[16];
  const float* Wout  = (const float*)d_in[17];
  const float* bout  = (const float*)d_in[18];
  float* out = (float*)d_out;

  // workspace layout (float offsets)
  float* ws = (float*)d_ws;
  __half*   h       = (__half*)ws;                 // N*128 halves (3.2M fl)
  float*    nodeB   = ws + 3200000;                // N*128 fp32   (6.4M fl)
  float*    asrc    = ws + 9600000;                // N*4
  float*    adst    = ws + 9800000;                // N*4
  int*      degT    = (int*)(ws + 10000000);       // 250k
  int*      offT    = (int*)(ws + 10250000);       // 250001
  int*      csr_src = (int*)(ws + 10500004);       // E_TOT
  int*      rank    = (int*)(ws + 11350004);       // E_TOT
  unsigned* pooled  = (unsigned*)(ws + 12200004);  // 64*128
  int*      bsum    = (int*)(ws + 12208196);       // 245
  int*      boff    = (int*)(ws + 12208452);       // 245

  const int* srcp = ei;
  const int* dstp = ei + E_EDGES;

  hipMemsetAsync(degT, 0, NSEG * sizeof(int), stream);

  // (dst, src_tile)-sorted CSR — built once, reused by all 3 layers
  k_hist<<<(E_TOT + 255) / 256, 256, 0, stream>>>(dstp, srcp, degT, rank);
  k_scanA<<<SCAN_BLOCKS, 256, 0, stream>>>(degT, bsum);
  k_scanB<<<1, 256, 0, stream>>>(bsum, boff, pooled);
  k_scanC<<<SCAN_BLOCKS, 256, 0, stream>>>(degT, boff, offT);
  k_scatter<<<(E_TOT + 255) / 256, 256, 0, stream>>>(srcp, dstp, offT, rank, csr_src);

  const float* lin_in = x;
  for (int L = 0; L < 3; L++) {
    k_gemm_mfma<<<(N_NODES + 63) / 64, 256, 0, stream>>>(
        lin_in, Wl[L], As[L], Ad[L], h, asrc, adst);
    k_aggr<<<(N_NODES * 64 + 255) / 256, 256, 0, stream>>>(
        offT, csr_src, asrc, adst, h, Bi[L], batch,
        nodeB, pooled, (L == 2) ? 1 : 0);
    lin_in = nodeB;
  }
  k_mlp<<<NG, 256, 0, stream>>>((const float*)pooled, Wlin, blin, Wout, bout, out);
}